// Round 7
// baseline (81.379 us; speedup 1.0000x reference)
//
#include <hip/hip_runtime.h>

#define R 128
#define C 256
#define P 7
#define HW 64

// ---- Kernel 1: transpose x[C][H][W] -> xt[H][W][C] (channel-contiguous) ----
// 1024 blocks: (h 0..63) x (16-channel group 0..15), 256 threads.
__global__ __launch_bounds__(256) void
transpose_kernel(const float* __restrict__ x, float* __restrict__ xt) {
    __shared__ float tile[16][68];            // stride 68: max 2-way alias (free)
    const int h  = blockIdx.x >> 4;
    const int c0 = (blockIdx.x & 15) << 4;
    const int t  = threadIdx.x;

    #pragma unroll
    for (int p = 0; p < 4; ++p) {             // load 16ch x 64w, coalesced in w
        const int cl = p * 4 + (t >> 6);
        const int w  = t & 63;
        tile[cl][w] = x[(size_t)(c0 + cl) * 4096 + (h << 6) + w];
    }
    __syncthreads();
    #pragma unroll
    for (int p = 0; p < 4; ++p) {             // write coalesced in (w,c) flat
        const int idx = p * 256 + t;
        const int w   = idx >> 4;
        const int cl  = idx & 15;
        xt[(size_t)(h << 14) + (w << 8) + c0 + cl] = tile[cl][w];
    }
}

// ---- Kernel 2: pool. Block = (r, 64-channel quarter), 512 threads. ----
// Reads channel-coalesced from xt; outputs staged in LDS, streamed out as
// 3136 contiguous floats (block-exclusive cache lines).
__global__ __launch_bounds__(512) void
pool_kernel(const float* __restrict__ xt, const int* __restrict__ rois,
            float* __restrict__ out) {
    __shared__ float obuf[64 * 49];           // [ch][bin], 12.25 KB
    const int tid  = threadIdx.x;
    const int lane = tid & 63;                // channel within quarter
    const int wid  = __builtin_amdgcn_readfirstlane(tid >> 6);  // 0..7
    const int r  = blockIdx.x >> 2;
    const int c0 = (blockIdx.x & 3) << 6;

    const int rx = rois[r * 4 + 0];           // scalar loads (r uniform)
    const int ry = rois[r * 4 + 1];
    const int rw = rois[r * 4 + 2];
    const int rh = rois[r * 4 + 3];

    // Match JAX: f32 rn divide; floor(coord + i*rl) with separate rn mul+add.
    const float rlx = (float)rw / 7.0f;
    const float rly = (float)rh / 7.0f;
    const int kw = __builtin_amdgcn_readfirstlane((int)rlx);   // floor(rl) >= 1
    const int kh = __builtin_amdgcn_readfirstlane((int)rly);

    const float* xq = xt + c0 + lane;
    const float NEG = -3.402823466e38f;

    for (int bin = wid; bin < 49; bin += 8) { // SALU loop, wave-uniform
        const int py = bin / 7;
        const int px = bin - py * 7;
        const int sx = __builtin_amdgcn_readfirstlane(
            (int)floorf(__fadd_rn((float)rx, __fmul_rn((float)px, rlx))));
        const int sy = __builtin_amdgcn_readfirstlane(
            (int)floorf(__fadd_rn((float)ry, __fmul_rn((float)py, rly))));
        // window fully in-bounds: sx+kw <= x+w <= 63, sy+kh <= y+h <= 63

        const float* p0 = xq + (((sy << 6) + sx) << 8);
        float m = NEG;
        #pragma unroll
        for (int iy = 0; iy < 8; ++iy) {
            if (iy < kh) {                    // wave-uniform branch
                #pragma unroll
                for (int ix = 0; ix < 8; ++ix)
                    if (ix < kw)              // wave-uniform branch
                        m = fmaxf(m, p0[((iy << 6) + ix) << 8]);  // 256B coalesced
            }
        }
        obuf[lane * 49 + bin] = m;            // stride-49 words: 2-way alias, free
    }
    __syncthreads();

    const size_t base = ((size_t)r * C + c0) * 49;
    for (int i = tid; i < 64 * 49; i += 512)  // contiguous, full-line stores
        out[base + i] = obuf[i];
}

extern "C" void kernel_launch(void* const* d_in, const int* in_sizes, int n_in,
                              void* d_out, int out_size, void* d_ws, size_t ws_size,
                              hipStream_t stream) {
    const float* x = (const float*)d_in[0];
    const int* rois = (const int*)d_in[1];
    float* out = (float*)d_out;
    float* xt = (float*)d_ws;                 // 64*64*256 floats = 4 MB scratch

    transpose_kernel<<<1024, 256, 0, stream>>>(x, xt);
    pool_kernel<<<R * 4, 512, 0, stream>>>(xt, rois, out);
}

// Round 8
// 23.161 us; speedup vs baseline: 3.5136x; 3.5136x over previous
//
#include <hip/hip_runtime.h>

#define R 128
#define C 256
#define P 7
#define HW 64

// ---- Kernel 1: transpose x[C][H][W] -> xt[H][W][C] ----
// 256 blocks = (h 0..63) x (64-ch group 0..3), 1024 threads (16 waves).
__global__ __launch_bounds__(1024) void
transpose_kernel(const float* __restrict__ x, float* __restrict__ xt) {
    __shared__ float tile[64][65];            // pad: conflict-free both phases
    const int h  = blockIdx.x >> 2;
    const int c0 = (blockIdx.x & 3) << 6;
    const int t  = threadIdx.x;
    const int a  = t & 63;                    // w (load) / c (store) lane axis
    const int q  = t >> 6;                    // 0..15

    #pragma unroll
    for (int p = 0; p < 4; ++p) {             // read: 256B coalesced along w
        const int cl = q * 4 + p;
        tile[cl][a] = x[(size_t)(c0 + cl) * 4096 + (h << 6) + a];
    }
    __syncthreads();
    #pragma unroll
    for (int p = 0; p < 4; ++p) {             // write: 256B coalesced along c
        const int w = q * 4 + p;
        xt[(size_t)(((h << 6) + w) << 8) + c0 + a] = tile[a][w];
    }
}

// ---- Kernel 2: pool from xt. Block = (r, 16-ch group), 256 threads. ----
// Lane = (bin, 4-ch float4). kw block-uniform -> switch-specialized row loads.
__global__ __launch_bounds__(256) void
pool_kernel(const float* __restrict__ xt, const int* __restrict__ rois,
            float* __restrict__ out) {
    __shared__ float obuf[16 * 49];           // [ch][bin], 3.1 KB
    const int tid = threadIdx.x;
    const int r   = blockIdx.x >> 4;
    const int c0  = (blockIdx.x & 15) << 4;

    const int rx = rois[r * 4 + 0];           // r uniform -> s_loads
    const int ry = rois[r * 4 + 1];
    const int rw = rois[r * 4 + 2];
    const int rh = rois[r * 4 + 3];

    // Match JAX: f32 rn divide; floor(coord + i*rl) with separate rn mul+add.
    const float rlx = (float)rw / 7.0f;
    const float rly = (float)rh / 7.0f;
    const int kw = __builtin_amdgcn_readfirstlane((int)rlx);  // floor(rl) in [1,8]
    const int kh = __builtin_amdgcn_readfirstlane((int)rly);

    const int bin = tid >> 2;                 // 0..63 (49 active)
    const int lc  = (tid & 3) << 2;           // 0,4,8,12
    const bool act = bin < 49;

    const float NEG = -3.402823466e38f;
    float4 acc = make_float4(NEG, NEG, NEG, NEG);

    if (act) {
        const int py = bin / 7;
        const int px = bin - py * 7;
        const int sx = (int)floorf(__fadd_rn((float)rx, __fmul_rn((float)px, rlx)));
        const int sy = (int)floorf(__fadd_rn((float)ry, __fmul_rn((float)py, rly)));
        // windows always in-bounds: sx+kw-1 <= 62, sy+kh-1 <= 62
        const float* p0 = xt + (((sy << 6) + sx) << 8) + c0 + lc;

#define LD4(p, ix) (*reinterpret_cast<const float4*>((p) + ((ix) << 8)))
#define MAX4(a, b) make_float4(fmaxf((a).x,(b).x), fmaxf((a).y,(b).y), \
                               fmaxf((a).z,(b).z), fmaxf((a).w,(b).w))
#define ROWS(KW)                                                     \
        for (int iy = 0; iy < kh; ++iy) {                            \
            const float* p = p0 + (iy << 14);                        \
            float4 m = LD4(p, 0);                                    \
            _Pragma("unroll")                                        \
            for (int ix = 1; ix < (KW); ++ix) m = MAX4(m, LD4(p, ix)); \
            acc = MAX4(acc, m);                                      \
        }
        switch (kw) {                          // block-uniform: one branch total
            case 1: ROWS(1); break;
            case 2: ROWS(2); break;
            case 3: ROWS(3); break;
            case 4: ROWS(4); break;
            case 5: ROWS(5); break;
            case 6: ROWS(6); break;
            case 7: ROWS(7); break;
            default: ROWS(8); break;
        }
        obuf[(lc + 0) * 49 + bin] = acc.x;     // light bank aliasing (~2-way)
        obuf[(lc + 1) * 49 + bin] = acc.y;
        obuf[(lc + 2) * 49 + bin] = acc.z;
        obuf[(lc + 3) * 49 + bin] = acc.w;
    }
    __syncthreads();

    // 784 contiguous floats per block: coalesced, block-exclusive lines.
    const size_t base = ((size_t)(r << 8) + c0) * 49;
    #pragma unroll
    for (int i = 0; i < 4; ++i) {
        const int idx = i * 256 + tid;
        if (idx < 16 * 49) out[base + idx] = obuf[idx];
    }
}

extern "C" void kernel_launch(void* const* d_in, const int* in_sizes, int n_in,
                              void* d_out, int out_size, void* d_ws, size_t ws_size,
                              hipStream_t stream) {
    const float* x = (const float*)d_in[0];
    const int* rois = (const int*)d_in[1];
    float* out = (float*)d_out;
    float* xt = (float*)d_ws;                 // 64*64*256 floats = 4 MB scratch

    transpose_kernel<<<256, 1024, 0, stream>>>(x, xt);
    pool_kernel<<<R * 16, 256, 0, stream>>>(xt, rois, out);
}

// Round 9
// 17.011 us; speedup vs baseline: 4.7837x; 1.3615x over previous
//
#include <hip/hip_runtime.h>

#define R 128
#define C 256
#define P 7
#define HW 64
#define SW 72   // slab row stride (floats): max read index sx+7 <= 69 < 72

__global__ __launch_bounds__(256) void
roi_pool_kernel(const float* __restrict__ x,
                const int* __restrict__ rois,
                float* __restrict__ out) {
    const int lane = threadIdx.x & 63;
    const int wid  = __builtin_amdgcn_readfirstlane(threadIdx.x >> 6);
    const int gw   = blockIdx.x * 4 + wid;   // global wave id = r*C + c
    const int c = gw & (C - 1);
    const int r = gw >> 8;

    __shared__ float vmbuf[4][P * SW];       // 8.06 KB/block
    float* slab = vmbuf[wid];

    const int rx = rois[r * 4 + 0];          // r uniform -> s_loads
    const int ry = rois[r * 4 + 1];
    const int rw = rois[r * 4 + 2];
    const int rh = rois[r * 4 + 3];

    // Match JAX: f32 rn divide; floor(coord + i*rl) with separate rn mul+add.
    const float rlx = (float)rw / 7.0f;
    const float rly = (float)rh / 7.0f;
    const int kw = __builtin_amdgcn_readfirstlane((int)rlx);  // floor(rl), 1..8
    const int kh = __builtin_amdgcn_readfirstlane((int)rly);

    // Band starts: lane plays py for lanes 0..6, then readlane -> SGPR.
    const int syv = (int)floorf(__fadd_rn((float)ry, __fmul_rn((float)lane, rly)));

    const float* xc = x + (size_t)c * (HW * HW);
    const float NEG = -3.402823466e38f;

    // ---- Phase 1: vertical band maxes, lane = column (coalesced). ----
    // KH unconditional batched loads (always in-bounds: sy(6)+7 <= 62),
    // branch-free cndmask discard of rows >= kh.
#define BAND(PY, KH)                                                         \
    {                                                                        \
        const int sy = __builtin_amdgcn_readlane(syv, PY);                   \
        const float* p = xc + sy * HW + lane;                                \
        float v[KH];                                                         \
        _Pragma("unroll")                                                    \
        for (int j = 0; j < KH; ++j) v[j] = p[j * HW];                       \
        float vm = NEG;                                                      \
        _Pragma("unroll")                                                    \
        for (int j = 0; j < KH; ++j) vm = fmaxf(vm, (j < kh) ? v[j] : NEG);  \
        slab[PY * SW + lane] = vm;                                           \
    }

    if (kh <= 4) {
        BAND(0,4) BAND(1,4) BAND(2,4) BAND(3,4) BAND(4,4) BAND(5,4) BAND(6,4)
    } else {
        BAND(0,8) BAND(1,8) BAND(2,8) BAND(3,8) BAND(4,8) BAND(5,8) BAND(6,8)
    }
#undef BAND

    // ---- Phase 2: one lane per output bin; unconditional ds_reads. ----
    // (Same-wave DS producer/consumer: compiler orders via lgkmcnt.)
    if (lane < P * P) {
        const int py = lane / 7;
        const int px = lane - py * 7;
        const int sx = (int)floorf(__fadd_rn((float)rx, __fmul_rn((float)px, rlx)));
        const float* wp = slab + py * SW + sx;   // reads <= wp[7] < row end (72)
        float m = NEG;
        if (kw <= 4) {
            float v0 = wp[0], v1 = wp[1], v2 = wp[2], v3 = wp[3];
            m = v0;
            m = fmaxf(m, (1 < kw) ? v1 : NEG);
            m = fmaxf(m, (2 < kw) ? v2 : NEG);
            m = fmaxf(m, (3 < kw) ? v3 : NEG);
        } else {
            float v0 = wp[0], v1 = wp[1], v2 = wp[2], v3 = wp[3];
            float v4 = wp[4], v5 = wp[5], v6 = wp[6], v7 = wp[7];
            m = fmaxf(fmaxf(fmaxf(v0, v1), fmaxf(v2, v3)), v4);  // kw >= 5
            m = fmaxf(m, (5 < kw) ? v5 : NEG);
            m = fmaxf(m, (6 < kw) ? v6 : NEG);
            m = fmaxf(m, (7 < kw) ? v7 : NEG);
        }
        out[(size_t)gw * (P * P) + lane] = m;    // 196B contiguous per wave
    }
}

extern "C" void kernel_launch(void* const* d_in, const int* in_sizes, int n_in,
                              void* d_out, int out_size, void* d_ws, size_t ws_size,
                              hipStream_t stream) {
    const float* x = (const float*)d_in[0];
    const int* rois = (const int*)d_in[1];
    float* out = (float*)d_out;

    const int grid = (R * C) / 4;  // one wave per (r,c), 4 waves/block
    roi_pool_kernel<<<grid, 256, 0, stream>>>(x, rois, out);
}